// Round 1
// baseline (1003.227 us; speedup 1.0000x reference)
//
#include <hip/hip_runtime.h>

#define B_ 2
#define N_ 2048
#define C_ 1024
#define H_ 16
#define D_ 64
#define M_ (B_*N_)   // 4096

// ---------------- GEMM: C = A(M,K) @ W(K,N) + bias ----------------
// 128x128 tile, BK=16, 256 threads, 8x8 per thread (two 4x4 quadrants per axis)
__global__ __launch_bounds__(256) void sgemm_bias(
    const float* __restrict__ A, const float* __restrict__ W,
    const float* __restrict__ bias, float* __restrict__ C,
    int M, int N, int K)
{
    __shared__ float As[16][132];   // transposed A tile [k][m], +4 pad kills store conflicts
    __shared__ float Bs[16][128];   // B tile [k][n]
    const int t  = threadIdx.x;
    const int tx = t & 15, ty = t >> 4;
    const int bm = blockIdx.y * 128, bn = blockIdx.x * 128;

    float acc[8][8];
#pragma unroll
    for (int i = 0; i < 8; ++i)
#pragma unroll
        for (int j = 0; j < 8; ++j) acc[i][j] = 0.f;

    for (int k0 = 0; k0 < K; k0 += 16) {
        // A tile 128x16 -> As transposed. 512 float4, 2 per thread.
#pragma unroll
        for (int u = 0; u < 2; ++u) {
            int f = t + u * 256;
            int r = f >> 2;              // 0..127 (row in tile)
            int c = (f & 3) << 2;        // 0,4,8,12 (k in tile)
            float4 v = *(const float4*)(A + (size_t)(bm + r) * K + k0 + c);
            As[c + 0][r] = v.x; As[c + 1][r] = v.y;
            As[c + 2][r] = v.z; As[c + 3][r] = v.w;
        }
        // B tile 16x128 direct. 512 float4, 2 per thread.
#pragma unroll
        for (int u = 0; u < 2; ++u) {
            int f = t + u * 256;
            int r = f >> 5;              // 0..15
            int c = (f & 31) << 2;       // 0..124
            *(float4*)&Bs[r][c] = *(const float4*)(W + (size_t)(k0 + r) * N + bn + c);
        }
        __syncthreads();
#pragma unroll
        for (int kk = 0; kk < 16; ++kk) {
            float a[8], b[8];
            *(float4*)&a[0] = *(const float4*)&As[kk][ty * 4];
            *(float4*)&a[4] = *(const float4*)&As[kk][64 + ty * 4];
            *(float4*)&b[0] = *(const float4*)&Bs[kk][tx * 4];
            *(float4*)&b[4] = *(const float4*)&Bs[kk][64 + tx * 4];
#pragma unroll
            for (int i = 0; i < 8; ++i)
#pragma unroll
                for (int j = 0; j < 8; ++j)
                    acc[i][j] += a[i] * b[j];
        }
        __syncthreads();
    }
#pragma unroll
    for (int ih = 0; ih < 2; ++ih)
#pragma unroll
        for (int i = 0; i < 4; ++i) {
            int row = bm + ih * 64 + ty * 4 + i;
#pragma unroll
            for (int jh = 0; jh < 2; ++jh) {
                int col = bn + jh * 64 + tx * 4;
                float4 bv = *(const float4*)(bias + col);
                float4 v;
                v.x = acc[ih * 4 + i][jh * 4 + 0] + bv.x;
                v.y = acc[ih * 4 + i][jh * 4 + 1] + bv.y;
                v.z = acc[ih * 4 + i][jh * 4 + 2] + bv.z;
                v.w = acc[ih * 4 + i][jh * 4 + 3] + bv.w;
                *(float4*)(C + (size_t)row * N + col) = v;
            }
        }
}

// ---------------- QK RMSNorm (in-place on qkv buffer) ----------------
// one wave per (row, s, h) vector of D=64
__global__ __launch_bounds__(256) void rmsnorm_qk(
    float* __restrict__ qkv, const float* __restrict__ gq, const float* __restrict__ gk)
{
    const int t = threadIdx.x;
    const int lane = t & 63;
    const int vec = blockIdx.x * 4 + (t >> 6);   // 0 .. M_*2*H_
    const int row = vec >> 5;                    // 2*H = 32 vectors per row
    const int rem = vec & 31;
    const int s = rem >> 4;                      // 0 = q, 1 = k
    const int h = rem & 15;
    const size_t addr = (size_t)row * 3072 + s * 1024 + h * 64 + lane;
    float v = qkv[addr];
    float ss = v * v;
#pragma unroll
    for (int o = 32; o > 0; o >>= 1) ss += __shfl_xor(ss, o, 64);
    float inv = rsqrtf(fmaxf(ss, 1e-24f));
    const float* g = s ? gk : gq;
    qkv[addr] = v * inv * g[h * 64 + lane] * 8.0f;   // sqrt(D)=8
}

// ---------------- Flash attention, fp32 ----------------
// block = 256 threads, one (b,h) x 64-row Q tile; K tiles of 64.
// K and V time-share one LDS buffer (K transposed [d][j]; V row-major [k][d]).
__global__ __launch_bounds__(256) void attn_fwd(
    const float* __restrict__ qkv, float* __restrict__ attn_out)
{
    __shared__ float Qt[64][68];    // [d][i], Q scaled by 1/8
    __shared__ float KVs[64][68];   // K: [d][j]; then V: [k][d]
    __shared__ float Ss[64][68];    // S then P, [i][j]
    __shared__ float mS[64], lS[64], aS[64];

    const int t  = threadIdx.x;
    const int tx = t & 15, ty = t >> 4;
    const int qt = blockIdx.x & 31;       // N/64 = 32 q-tiles
    const int bh = blockIdx.x >> 5;
    const int b  = bh >> 4, h = bh & 15;

    const float* qbase = qkv + (size_t)(b * N_ + qt * 64) * 3072 + h * 64;
    const float* kbase = qkv + (size_t)(b * N_) * 3072 + 1024 + h * 64;
    const float* vbase = kbase + 1024;

    // Q load: scaled by 1/sqrt(D), transposed to [d][i]
#pragma unroll
    for (int u = 0; u < 4; ++u) {
        int f = t + u * 256;
        int r = f >> 4;               // 0..63 query row
        int c = (f & 15) << 2;        // d
        float4 v = *(const float4*)(qbase + (size_t)r * 3072 + c);
        Qt[c + 0][r] = v.x * 0.125f; Qt[c + 1][r] = v.y * 0.125f;
        Qt[c + 2][r] = v.z * 0.125f; Qt[c + 3][r] = v.w * 0.125f;
    }
    if (t < 64) { mS[t] = -3.0e38f; lS[t] = 0.f; }
    float O[4][4];
#pragma unroll
    for (int i = 0; i < 4; ++i)
#pragma unroll
        for (int j = 0; j < 4; ++j) O[i][j] = 0.f;
    __syncthreads();

    for (int kt = 0; kt < 32; ++kt) {
        // K tile load, transposed to [d][j]
#pragma unroll
        for (int u = 0; u < 4; ++u) {
            int f = t + u * 256;
            int r = f >> 4;
            int c = (f & 15) << 2;
            float4 v = *(const float4*)(kbase + (size_t)(kt * 64 + r) * 3072 + c);
            KVs[c + 0][r] = v.x; KVs[c + 1][r] = v.y;
            KVs[c + 2][r] = v.z; KVs[c + 3][r] = v.w;
        }
        __syncthreads();

        // S[i][j] = sum_d Qt[d][i] * Kt[d][j]
        float s[4][4];
#pragma unroll
        for (int i = 0; i < 4; ++i)
#pragma unroll
            for (int j = 0; j < 4; ++j) s[i][j] = 0.f;
#pragma unroll
        for (int d = 0; d < 64; ++d) {
            float a[4], bb[4];
            *(float4*)a  = *(const float4*)&Qt[d][ty * 4];
            *(float4*)bb = *(const float4*)&KVs[d][tx * 4];
#pragma unroll
            for (int i = 0; i < 4; ++i)
#pragma unroll
                for (int j = 0; j < 4; ++j)
                    s[i][j] += a[i] * bb[j];
        }
#pragma unroll
        for (int i = 0; i < 4; ++i) {
            float4 v; v.x = s[i][0]; v.y = s[i][1]; v.z = s[i][2]; v.w = s[i][3];
            *(float4*)&Ss[ty * 4 + i][tx * 4] = v;
        }
        __syncthreads();

        // V tile -> regs (hide latency under softmax)
        float4 vreg[4]; int vr[4], vc[4];
#pragma unroll
        for (int u = 0; u < 4; ++u) {
            int f = t + u * 256;
            vr[u] = f >> 4;
            vc[u] = (f & 15) << 2;
            vreg[u] = *(const float4*)(vbase + (size_t)(kt * 64 + vr[u]) * 3072 + vc[u]);
        }

        // online softmax: 4 threads per row, 16 cols each
        {
            int rid = t >> 2, sub = t & 3;
            float mo = mS[rid];
            float mx = -3.0e38f;
#pragma unroll
            for (int j = 0; j < 16; ++j) mx = fmaxf(mx, Ss[rid][sub * 16 + j]);
            mx = fmaxf(mx, __shfl_xor(mx, 1, 64));
            mx = fmaxf(mx, __shfl_xor(mx, 2, 64));
            float mn = fmaxf(mo, mx);
            float sum = 0.f;
#pragma unroll
            for (int j = 0; j < 16; ++j) {
                float p = __expf(Ss[rid][sub * 16 + j] - mn);
                Ss[rid][sub * 16 + j] = p;
                sum += p;
            }
            sum += __shfl_xor(sum, 1, 64);
            sum += __shfl_xor(sum, 2, 64);
            if (sub == 0) {
                float al = __expf(mo - mn);
                aS[rid] = al;
                mS[rid] = mn;
                lS[rid] = lS[rid] * al + sum;
            }
        }
        // V regs -> KVs (K no longer needed; all K readers passed the barrier above)
#pragma unroll
        for (int u = 0; u < 4; ++u)
            *(float4*)&KVs[vr[u]][vc[u]] = vreg[u];
        __syncthreads();

        // O = O*alpha + P @ V
        {
            float al[4];
#pragma unroll
            for (int i = 0; i < 4; ++i) al[i] = aS[ty * 4 + i];
#pragma unroll
            for (int i = 0; i < 4; ++i)
#pragma unroll
                for (int j = 0; j < 4; ++j) O[i][j] *= al[i];
#pragma unroll
            for (int kk = 0; kk < 64; ++kk) {
                float p[4], vv[4];
#pragma unroll
                for (int i = 0; i < 4; ++i) p[i] = Ss[ty * 4 + i][kk];
                *(float4*)vv = *(const float4*)&KVs[kk][tx * 4];
#pragma unroll
                for (int i = 0; i < 4; ++i)
#pragma unroll
                    for (int j = 0; j < 4; ++j)
                        O[i][j] += p[i] * vv[j];
            }
        }
        __syncthreads();
    }

    // epilogue: O / l -> attn_out (B,N,H,D) flattened as (M, C)
#pragma unroll
    for (int i = 0; i < 4; ++i) {
        int row = b * N_ + qt * 64 + ty * 4 + i;
        float linv = 1.0f / lS[ty * 4 + i];
        float4 v;
        v.x = O[i][0] * linv; v.y = O[i][1] * linv;
        v.z = O[i][2] * linv; v.w = O[i][3] * linv;
        *(float4*)(attn_out + (size_t)row * 1024 + h * 64 + tx * 4) = v;
    }
}

extern "C" void kernel_launch(void* const* d_in, const int* in_sizes, int n_in,
                              void* d_out, int out_size, void* d_ws, size_t ws_size,
                              hipStream_t stream)
{
    const float* x    = (const float*)d_in[0];
    const float* Wqkv = (const float*)d_in[1];
    const float* bqkv = (const float*)d_in[2];
    const float* gq   = (const float*)d_in[3];
    const float* gk   = (const float*)d_in[4];
    const float* Wout = (const float*)d_in[5];
    const float* bout = (const float*)d_in[6];
    float* out  = (float*)d_out;
    float* qkv  = (float*)d_ws;                        // M_*3072 floats (48 MB)
    float* attn = qkv + (size_t)M_ * 3072;             // M_*1024 floats (16 MB)

    // 1) QKV projection + bias
    sgemm_bias<<<dim3(3072 / 128, M_ / 128), 256, 0, stream>>>(
        x, Wqkv, bqkv, qkv, M_, 3072, 1024);
    // 2) RMS-norm q and k in place
    rmsnorm_qk<<<dim3((M_ * 2 * H_) / 4), 256, 0, stream>>>(qkv, gq, gk);
    // 3) attention
    attn_fwd<<<dim3((N_ / 64) * B_ * H_), 256, 0, stream>>>(qkv, attn);
    // 4) output projection + bias
    sgemm_bias<<<dim3(1024 / 128, M_ / 128), 256, 0, stream>>>(
        attn, Wout, bout, out, M_, 1024, 1024);
}

// Round 2
// 225.633 us; speedup vs baseline: 4.4463x; 4.4463x over previous
//
#include <hip/hip_runtime.h>

#define B_ 2
#define N_ 2048
#define C_ 1024
#define H_ 16
#define D_ 64
#define M_ (B_*N_)   // 4096
#define LOG2E 1.44269504088896340736f

typedef __bf16 bf16x8 __attribute__((ext_vector_type(8)));
typedef float  f32x4  __attribute__((ext_vector_type(4)));
typedef unsigned short u16;

#define MFMA16(a, b, c) __builtin_amdgcn_mfma_f32_16x16x32_bf16(a, b, c, 0, 0, 0)

__device__ __forceinline__ u16 f2b(float f) {
    union { float f; unsigned int u; } v; v.f = f;
    unsigned int r = (v.u + 0x7fffu + ((v.u >> 16) & 1u)) >> 16;
    return (u16)r;
}
__device__ __forceinline__ float b2f(u16 h) {
    union { unsigned int u; float f; } v; v.u = ((unsigned int)h) << 16;
    return v.f;
}
__device__ __forceinline__ void gload16(const void* g, void* lds) {
    __builtin_amdgcn_global_load_lds(
        (const __attribute__((address_space(1))) unsigned int*)g,
        (__attribute__((address_space(3))) unsigned int*)lds, 16, 0, 0);
}

// ---------------- x f32 -> bf16 ----------------
__global__ __launch_bounds__(256) void cvt_f32_bf16(
    const float* __restrict__ src, u16* __restrict__ dst, int n8)
{
    int i = blockIdx.x * 256 + threadIdx.x;
    if (i >= n8) return;
    float4 a = *(const float4*)(src + (size_t)i * 8);
    float4 b = *(const float4*)(src + (size_t)i * 8 + 4);
    u16 tmp[8] = { f2b(a.x), f2b(a.y), f2b(a.z), f2b(a.w),
                   f2b(b.x), f2b(b.y), f2b(b.z), f2b(b.w) };
    *(uint4*)(dst + (size_t)i * 8) = *(uint4*)tmp;
}

// ---------------- W f32 [K][N] -> bf16 [N][K] (transpose) ----------------
__global__ __launch_bounds__(256) void cvt_wT(
    const float* __restrict__ W, u16* __restrict__ Wt, int K, int N)
{
    __shared__ u16 T[64][72];
    const int t = threadIdx.x;
    const int ntiles = N >> 6;
    const int kt = blockIdx.x / ntiles, ntl = blockIdx.x % ntiles;
#pragma unroll
    for (int u = 0; u < 2; ++u) {
        int f = t + u * 256;
        int r = f >> 3, c = f & 7;
        const float* p = W + (size_t)(kt * 64 + r) * N + ntl * 64 + c * 8;
        float4 a = *(const float4*)p;
        float4 b = *(const float4*)(p + 4);
        u16 tmp[8] = { f2b(a.x), f2b(a.y), f2b(a.z), f2b(a.w),
                       f2b(b.x), f2b(b.y), f2b(b.z), f2b(b.w) };
        *(uint4*)&T[r][c * 8] = *(uint4*)tmp;
    }
    __syncthreads();
    int n = t >> 2;
    u16 tmp[16];
#pragma unroll
    for (int i = 0; i < 16; ++i) tmp[i] = T[(t & 3) * 16 + i][n];
    u16* o = Wt + (size_t)(ntl * 64 + n) * K + kt * 64 + (t & 3) * 16;
    *(uint4*)o       = *(uint4*)&tmp[0];
    *(uint4*)(o + 8) = *(uint4*)&tmp[8];
}

// ---------------- GEMM bf16 MFMA: A[M][K] @ Bt[N][K]^T + bias ----------------
// 128x128 tile, BK=32, 4 waves (2x2), 16x16x32 MFMA, global_load_lds + xor swizzle
__global__ __launch_bounds__(256) void gemm_bf16(
    const u16* __restrict__ A, const u16* __restrict__ Bt,
    const float* __restrict__ bias, void* __restrict__ Cout,
    int M, int N, int K, int bf16out)
{
    __shared__ u16 Al[2][128 * 32];
    __shared__ u16 Bl[2][128 * 32];
    const int t = threadIdx.x, l = t & 63, w = t >> 6;
    const int wr = w >> 1, wc = w & 1;
    const int bm = blockIdx.y * 128, bn = blockIdx.x * 128;

    f32x4 acc[4][4];
#pragma unroll
    for (int i = 0; i < 4; ++i)
#pragma unroll
        for (int j = 0; j < 4; ++j) acc[i][j] = (f32x4){0.f, 0.f, 0.f, 0.f};

    const int srow = (l >> 2);            // 0..15 within staging instr
    const int schunk = (l & 3) ^ ((l >> 2) & 3);

    auto stage = [&](int buf, int k0) {
#pragma unroll
        for (int u = 0; u < 2; ++u) {
            int p = w * 2 + u;                    // 0..7 -> rows 16p..16p+15
            int r = p * 16 + srow;
            gload16(A + (size_t)(bm + r) * K + k0 + schunk * 8, &Al[buf][p * 512]);
            gload16(Bt + (size_t)(bn + r) * K + k0 + schunk * 8, &Bl[buf][p * 512]);
        }
    };

    stage(0, 0);
    const int NT = K / 32;
    const int g = l >> 4;
    for (int tt = 0; tt < NT; ++tt) {
        if (tt + 1 < NT) stage((tt + 1) & 1, (tt + 1) * 32);
        __syncthreads();
        const u16* al = &Al[tt & 1][0];
        const u16* bl = &Bl[tt & 1][0];
        bf16x8 af[4], bf[4];
#pragma unroll
        for (int mb = 0; mb < 4; ++mb) {
            int r = wr * 64 + mb * 16 + (l & 15);
            af[mb] = *(const bf16x8*)(al + r * 32 + ((g ^ (r & 3)) << 3));
            int n = wc * 64 + mb * 16 + (l & 15);
            bf[mb] = *(const bf16x8*)(bl + n * 32 + ((g ^ (n & 3)) << 3));
        }
#pragma unroll
        for (int mb = 0; mb < 4; ++mb)
#pragma unroll
            for (int nb = 0; nb < 4; ++nb)
                acc[mb][nb] = MFMA16(af[mb], bf[nb], acc[mb][nb]);
        __syncthreads();
    }

#pragma unroll
    for (int mb = 0; mb < 4; ++mb) {
        int row = bm + wr * 64 + mb * 16 + (l >> 4) * 4;
#pragma unroll
        for (int nb = 0; nb < 4; ++nb) {
            int col = bn + wc * 64 + nb * 16 + (l & 15);
            float bv = bias[col];
#pragma unroll
            for (int r = 0; r < 4; ++r) {
                float v = acc[mb][nb][r] + bv;
                if (bf16out) ((u16*)Cout)[(size_t)(row + r) * N + col] = f2b(v);
                else        ((float*)Cout)[(size_t)(row + r) * N + col] = v;
            }
        }
    }
}

// ---------------- RMSNorm q,k from bf16 qkv; q folds 1/sqrt(D) ----------------
__global__ __launch_bounds__(256) void rmsnorm_qk_b(
    const u16* __restrict__ qkvb, const float* __restrict__ gq,
    const float* __restrict__ gk, u16* __restrict__ qb, u16* __restrict__ kb)
{
    const int t = threadIdx.x, lane = t & 63;
    const int vec = blockIdx.x * 4 + (t >> 6);
    const int row = vec >> 5;
    const int rem = vec & 31;
    const int s = rem >> 4, h = rem & 15;
    float v = b2f(qkvb[(size_t)row * 3072 + s * 1024 + h * 64 + lane]);
    float ss = v * v;
#pragma unroll
    for (int o = 32; o > 0; o >>= 1) ss += __shfl_xor(ss, o, 64);
    float inv = rsqrtf(fmaxf(ss, 1e-24f));
    const float* gm = s ? gk : gq;
    float scale = s ? 8.0f : 1.0f;   // q: *8 (sqrt D) * 1/8 (softmax scale) = 1
    u16* outp = s ? kb : qb;
    outp[(size_t)row * 1024 + h * 64 + lane] = f2b(v * inv * gm[h * 64 + lane] * scale);
}

// ---------------- V -> Vt global transpose: vt[bh][d][n] ----------------
__global__ __launch_bounds__(256) void v_transpose(
    const u16* __restrict__ qkvb, u16* __restrict__ vt)
{
    __shared__ u16 T[64][72];
    const int t = threadIdx.x;
    const int nt = blockIdx.x & 31;
    const int bh = blockIdx.x >> 5;
    const int b = bh >> 4, h = bh & 15;
#pragma unroll
    for (int u = 0; u < 2; ++u) {
        int f = t + u * 256;
        int n = f >> 3, c = f & 7;
        uint4 v = *(const uint4*)(qkvb + (size_t)(b * 2048 + nt * 64 + n) * 3072 + 2048 + h * 64 + c * 8);
        *(uint4*)&T[n][c * 8] = v;
    }
    __syncthreads();
    int d = t >> 2;
    u16 tmp[16];
#pragma unroll
    for (int i = 0; i < 16; ++i) tmp[i] = T[(t & 3) * 16 + i][d];
    u16* o = vt + ((size_t)bh * 64 + d) * 2048 + nt * 64 + (t & 3) * 16;
    *(uint4*)o       = *(uint4*)&tmp[0];
    *(uint4*)(o + 8) = *(uint4*)&tmp[8];
}

// ---------------- Flash attention, bf16 MFMA ----------------
// block: 4 waves, Q tile = 128 rows (32/wave), KV tile = 64, D = 64
__global__ __launch_bounds__(256) void attn_mfma(
    const u16* __restrict__ qb, const u16* __restrict__ kb,
    const u16* __restrict__ vt, u16* __restrict__ attnb)
{
    __shared__ u16 Kl[2][64 * 64];
    __shared__ u16 Vl[2][64 * 64];
    __shared__ u16 Pl[4][32 * 72];

    const int t = threadIdx.x, l = t & 63, w = t >> 6;
    const int qt = blockIdx.x & 15;        // N/128
    const int bh = blockIdx.x >> 4;
    const int b = bh >> 4, h = bh & 15;
    const int g = l >> 4;

    // Q fragments (1/sqrt(D) already folded into qb)
    bf16x8 qf[2][2];
#pragma unroll
    for (int mb = 0; mb < 2; ++mb) {
        int qrow = b * 2048 + qt * 128 + w * 32 + mb * 16 + (l & 15);
#pragma unroll
        for (int g2 = 0; g2 < 2; ++g2)
            qf[mb][g2] = *(const bf16x8*)(qb + (size_t)qrow * 1024 + h * 64 + g2 * 32 + g * 8);
    }

    f32x4 O[2][4];
#pragma unroll
    for (int i = 0; i < 2; ++i)
#pragma unroll
        for (int j = 0; j < 4; ++j) O[i][j] = (f32x4){0.f, 0.f, 0.f, 0.f};
    float mrow[2][4], lrow[2][4];
#pragma unroll
    for (int i = 0; i < 2; ++i)
#pragma unroll
        for (int r = 0; r < 4; ++r) { mrow[i][r] = -3.0e38f; lrow[i][r] = 0.f; }

    auto stageKV = [&](int buf, int kt) {
#pragma unroll
        for (int u = 0; u < 2; ++u) {
            int p = w * 2 + u;                 // 0..7 -> rows 8p..8p+7
            int row = p * 8 + (l >> 3);
            int chunk = (l & 7) ^ (row & 7);
            gload16(kb + (size_t)(b * 2048 + kt * 64 + row) * 1024 + h * 64 + chunk * 8,
                    &Kl[buf][p * 512]);
            gload16(vt + ((size_t)bh * 64 + row) * 2048 + kt * 64 + chunk * 8,
                    &Vl[buf][p * 512]);
        }
    };

    stageKV(0, 0);
    for (int kt = 0; kt < 32; ++kt) {
        if (kt + 1 < 32) stageKV((kt + 1) & 1, kt + 1);
        __syncthreads();
        const u16* kl = &Kl[kt & 1][0];
        const u16* vl = &Vl[kt & 1][0];

        // S = Q @ K^T
        f32x4 S[2][4];
#pragma unroll
        for (int i = 0; i < 2; ++i)
#pragma unroll
            for (int j = 0; j < 4; ++j) S[i][j] = (f32x4){0.f, 0.f, 0.f, 0.f};
#pragma unroll
        for (int cb = 0; cb < 4; ++cb) {
            int krow = cb * 16 + (l & 15);
#pragma unroll
            for (int g2 = 0; g2 < 2; ++g2) {
                int chunk = 4 * g2 + g;
                bf16x8 kf = *(const bf16x8*)(kl + krow * 64 + ((chunk ^ (krow & 7)) << 3));
#pragma unroll
                for (int mb = 0; mb < 2; ++mb)
                    S[mb][cb] = MFMA16(qf[mb][g2], kf, S[mb][cb]);
            }
        }

        // online softmax (rows live on 16-lane groups) + P -> LDS (bf16)
#pragma unroll
        for (int mb = 0; mb < 2; ++mb) {
#pragma unroll
            for (int r = 0; r < 4; ++r) {
                float mx = fmaxf(fmaxf(S[mb][0][r], S[mb][1][r]),
                                 fmaxf(S[mb][2][r], S[mb][3][r]));
                mx = fmaxf(mx, __shfl_xor(mx, 1, 64));
                mx = fmaxf(mx, __shfl_xor(mx, 2, 64));
                mx = fmaxf(mx, __shfl_xor(mx, 4, 64));
                mx = fmaxf(mx, __shfl_xor(mx, 8, 64));
                float mo = mrow[mb][r];
                float mn = fmaxf(mo, mx);
                float al = exp2f((mo - mn) * LOG2E);
                float sum = 0.f;
                u16 pb[4];
#pragma unroll
                for (int cb = 0; cb < 4; ++cb) {
                    float p = exp2f((S[mb][cb][r] - mn) * LOG2E);
                    sum += p;
                    pb[cb] = f2b(p);
                }
                sum += __shfl_xor(sum, 1, 64);
                sum += __shfl_xor(sum, 2, 64);
                sum += __shfl_xor(sum, 4, 64);
                sum += __shfl_xor(sum, 8, 64);
                mrow[mb][r] = mn;
                lrow[mb][r] = lrow[mb][r] * al + sum;
#pragma unroll
                for (int db = 0; db < 4; ++db) O[mb][db][r] *= al;
                int prow = mb * 16 + g * 4 + r;
#pragma unroll
                for (int cb = 0; cb < 4; ++cb)
                    Pl[w][prow * 72 + cb * 16 + (l & 15)] = pb[cb];
            }
        }

        // O += P @ V
#pragma unroll
        for (int ks = 0; ks < 2; ++ks) {
            bf16x8 pa[2];
#pragma unroll
            for (int mb = 0; mb < 2; ++mb)
                pa[mb] = *(const bf16x8*)(&Pl[w][(mb * 16 + (l & 15)) * 72 + ks * 32 + g * 8]);
#pragma unroll
            for (int db = 0; db < 4; ++db) {
                int vrow = db * 16 + (l & 15);
                int chunk = 4 * ks + g;
                bf16x8 vf = *(const bf16x8*)(vl + vrow * 64 + ((chunk ^ (vrow & 7)) << 3));
#pragma unroll
                for (int mb = 0; mb < 2; ++mb)
                    O[mb][db] = MFMA16(pa[mb], vf, O[mb][db]);
            }
        }
        __syncthreads();
    }

    // epilogue: O / l -> attnb bf16
#pragma unroll
    for (int mb = 0; mb < 2; ++mb) {
#pragma unroll
        for (int r = 0; r < 4; ++r) {
            int qrow = b * 2048 + qt * 128 + w * 32 + mb * 16 + g * 4 + r;
            float linv = 1.0f / lrow[mb][r];
#pragma unroll
            for (int db = 0; db < 4; ++db)
                attnb[(size_t)qrow * 1024 + h * 64 + db * 16 + (l & 15)] =
                    f2b(O[mb][db][r] * linv);
        }
    }
}

extern "C" void kernel_launch(void* const* d_in, const int* in_sizes, int n_in,
                              void* d_out, int out_size, void* d_ws, size_t ws_size,
                              hipStream_t stream)
{
    const float* x    = (const float*)d_in[0];
    const float* Wqkv = (const float*)d_in[1];
    const float* bqkv = (const float*)d_in[2];
    const float* gq   = (const float*)d_in[3];
    const float* gk   = (const float*)d_in[4];
    const float* Wout = (const float*)d_in[5];
    const float* bout = (const float*)d_in[6];
    float* out = (float*)d_out;

    char* ws = (char*)d_ws;
    u16* xb     = (u16*)(ws);                       // 8 MB
    u16* wqkvt  = (u16*)(ws + (8u << 20));          // 6 MB
    u16* woutt  = (u16*)(ws + (14u << 20));         // 2 MB
    u16* qkvb   = (u16*)(ws + (16u << 20));         // 24 MB
    u16* attnb  = (u16*)(ws + (16u << 20));         // 8 MB (overlays qkvb, used after)
    u16* qbuf   = (u16*)(ws + (40u << 20));         // 8 MB
    u16* kbuf   = (u16*)(ws + (48u << 20));         // 8 MB
    u16* vtb    = (u16*)(ws + (56u << 20));         // 8 MB  => 64 MB total

    cvt_f32_bf16<<<2048, 256, 0, stream>>>(x, xb, M_ * C_ / 8);
    cvt_wT<<<16 * 48, 256, 0, stream>>>(Wqkv, wqkvt, 1024, 3072);
    cvt_wT<<<16 * 16, 256, 0, stream>>>(Wout, woutt, 1024, 1024);

    gemm_bf16<<<dim3(24, 32), 256, 0, stream>>>(xb, wqkvt, bqkv, qkvb, M_, 3072, 1024, 1);
    rmsnorm_qk_b<<<32768, 256, 0, stream>>>(qkvb, gq, gk, qbuf, kbuf);
    v_transpose<<<1024, 256, 0, stream>>>(qkvb, vtb);
    attn_mfma<<<512, 256, 0, stream>>>(qbuf, kbuf, vtb, attnb);
    gemm_bf16<<<dim3(8, 32), 256, 0, stream>>>(attnb, woutt, bout, out, M_, 1024, 1024, 0);
}

// Round 4
// 174.098 us; speedup vs baseline: 5.7624x; 1.2960x over previous
//
#include <hip/hip_runtime.h>

#define B_ 2
#define N_ 2048
#define C_ 1024
#define H_ 16
#define D_ 64
#define M_ (B_*N_)   // 4096
#define LOG2E 1.44269504088896340736f

typedef __bf16 bf16x8 __attribute__((ext_vector_type(8)));
typedef float  f32x4  __attribute__((ext_vector_type(4)));
typedef float  f32x16 __attribute__((ext_vector_type(16)));
typedef unsigned short u16;

#define MFMA16(a, b, c) __builtin_amdgcn_mfma_f32_16x16x32_bf16(a, b, c, 0, 0, 0)
#define MFMA32(a, b, c) __builtin_amdgcn_mfma_f32_32x32x16_bf16(a, b, c, 0, 0, 0)

__device__ __forceinline__ u16 f2b(float f) {
    union { float f; unsigned int u; } v; v.f = f;
    unsigned int r = (v.u + 0x7fffu + ((v.u >> 16) & 1u)) >> 16;
    return (u16)r;
}
__device__ __forceinline__ float b2f(u16 h) {
    union { unsigned int u; float f; } v; v.u = ((unsigned int)h) << 16;
    return v.f;
}
__device__ __forceinline__ void gload16(const void* g, void* lds) {
    __builtin_amdgcn_global_load_lds(
        (const __attribute__((address_space(1))) unsigned int*)g,
        (__attribute__((address_space(3))) unsigned int*)lds, 16, 0, 0);
}

// ---------------- x f32 -> bf16 ----------------
__global__ __launch_bounds__(256) void cvt_f32_bf16(
    const float* __restrict__ src, u16* __restrict__ dst, int n8)
{
    int i = blockIdx.x * 256 + threadIdx.x;
    if (i >= n8) return;
    float4 a = *(const float4*)(src + (size_t)i * 8);
    float4 b = *(const float4*)(src + (size_t)i * 8 + 4);
    u16 tmp[8] = { f2b(a.x), f2b(a.y), f2b(a.z), f2b(a.w),
                   f2b(b.x), f2b(b.y), f2b(b.z), f2b(b.w) };
    *(uint4*)(dst + (size_t)i * 8) = *(uint4*)tmp;
}

// ---------------- W f32 [K][N] -> bf16 [N][K] (transpose) ----------------
__global__ __launch_bounds__(256) void cvt_wT(
    const float* __restrict__ W, u16* __restrict__ Wt, int K, int N)
{
    __shared__ u16 T[64][72];
    const int t = threadIdx.x;
    const int ntiles = N >> 6;
    const int kt = blockIdx.x / ntiles, ntl = blockIdx.x % ntiles;
#pragma unroll
    for (int u = 0; u < 2; ++u) {
        int f = t + u * 256;
        int r = f >> 3, c = f & 7;
        const float* p = W + (size_t)(kt * 64 + r) * N + ntl * 64 + c * 8;
        float4 a = *(const float4*)p;
        float4 b = *(const float4*)(p + 4);
        u16 tmp[8] = { f2b(a.x), f2b(a.y), f2b(a.z), f2b(a.w),
                       f2b(b.x), f2b(b.y), f2b(b.z), f2b(b.w) };
        *(uint4*)&T[r][c * 8] = *(uint4*)tmp;
    }
    __syncthreads();
    int n = t >> 2;
    u16 tmp[16];
#pragma unroll
    for (int i = 0; i < 16; ++i) tmp[i] = T[(t & 3) * 16 + i][n];
    u16* o = Wt + (size_t)(ntl * 64 + n) * K + kt * 64 + (t & 3) * 16;
    *(uint4*)o       = *(uint4*)&tmp[0];
    *(uint4*)(o + 8) = *(uint4*)&tmp[8];
}

// ---------------- GEMM bf16 MFMA: A[M][K] @ Bt[N][K]^T + bias ----------------
__global__ __launch_bounds__(256) void gemm_bf16(
    const u16* __restrict__ A, const u16* __restrict__ Bt,
    const float* __restrict__ bias, void* __restrict__ Cout,
    int M, int N, int K, int bf16out)
{
    __shared__ u16 Al[2][128 * 32];
    __shared__ u16 Bl[2][128 * 32];
    const int t = threadIdx.x, l = t & 63, w = t >> 6;
    const int wr = w >> 1, wc = w & 1;
    const int bm = blockIdx.y * 128, bn = blockIdx.x * 128;

    f32x4 acc[4][4];
#pragma unroll
    for (int i = 0; i < 4; ++i)
#pragma unroll
        for (int j = 0; j < 4; ++j) acc[i][j] = (f32x4){0.f, 0.f, 0.f, 0.f};

    const int srow = (l >> 2);
    const int schunk = (l & 3) ^ ((l >> 2) & 3);

    auto stage = [&](int buf, int k0) {
#pragma unroll
        for (int u = 0; u < 2; ++u) {
            int p = w * 2 + u;
            int r = p * 16 + srow;
            gload16(A + (size_t)(bm + r) * K + k0 + schunk * 8, &Al[buf][p * 512]);
            gload16(Bt + (size_t)(bn + r) * K + k0 + schunk * 8, &Bl[buf][p * 512]);
        }
    };

    stage(0, 0);
    const int NT = K / 32;
    const int g = l >> 4;
    for (int tt = 0; tt < NT; ++tt) {
        __syncthreads();                       // drains stage(tt); readers of buf[(tt+1)&1] done
        if (tt + 1 < NT) stage((tt + 1) & 1, (tt + 1) * 32);   // overlaps compute below
        const u16* al = &Al[tt & 1][0];
        const u16* bl = &Bl[tt & 1][0];
        bf16x8 af[4], bf[4];
#pragma unroll
        for (int mb = 0; mb < 4; ++mb) {
            int r = wr * 64 + mb * 16 + (l & 15);
            af[mb] = *(const bf16x8*)(al + r * 32 + ((g ^ (r & 3)) << 3));
            int n = wc * 64 + mb * 16 + (l & 15);
            bf[mb] = *(const bf16x8*)(bl + n * 32 + ((g ^ (n & 3)) << 3));
        }
#pragma unroll
        for (int mb = 0; mb < 4; ++mb)
#pragma unroll
            for (int nb = 0; nb < 4; ++nb)
                acc[mb][nb] = MFMA16(af[mb], bf[nb], acc[mb][nb]);
    }

#pragma unroll
    for (int mb = 0; mb < 4; ++mb) {
        int row = bm + wr * 64 + mb * 16 + (l >> 4) * 4;
#pragma unroll
        for (int nb = 0; nb < 4; ++nb) {
            int col = bn + wc * 64 + nb * 16 + (l & 15);
            float bv = bias[col];
#pragma unroll
            for (int r = 0; r < 4; ++r) {
                float v = acc[mb][nb][r] + bv;
                if (bf16out) ((u16*)Cout)[(size_t)(row + r) * N + col] = f2b(v);
                else        ((float*)Cout)[(size_t)(row + r) * N + col] = v;
            }
        }
    }
}

// ---------------- RMSNorm q,k; q folds softmax scale AND log2(e) ----------------
__global__ __launch_bounds__(256) void rmsnorm_qk_b(
    const u16* __restrict__ qkvb, const float* __restrict__ gq,
    const float* __restrict__ gk, u16* __restrict__ qb, u16* __restrict__ kb)
{
    const int t = threadIdx.x, lane = t & 63;
    const int vec = blockIdx.x * 4 + (t >> 6);
    const int row = vec >> 5;
    const int rem = vec & 31;
    const int s = rem >> 4, h = rem & 15;
    float v = b2f(qkvb[(size_t)row * 3072 + s * 1024 + h * 64 + lane]);
    float ss = v * v;
#pragma unroll
    for (int o = 32; o > 0; o >>= 1) ss += __shfl_xor(ss, o, 64);
    float inv = rsqrtf(fmaxf(ss, 1e-24f));
    const float* gm = s ? gk : gq;
    float scale = s ? 8.0f : LOG2E;   // q: sqrtD * 1/sqrtD * log2e
    u16* outp = s ? kb : qb;
    outp[(size_t)row * 1024 + h * 64 + lane] = f2b(v * inv * gm[h * 64 + lane] * scale);
}

// ---------------- V -> Vt global transpose: vt[bh][d][n] ----------------
__global__ __launch_bounds__(256) void v_transpose(
    const u16* __restrict__ qkvb, u16* __restrict__ vt)
{
    __shared__ u16 T[64][72];
    const int t = threadIdx.x;
    const int nt = blockIdx.x & 31;
    const int bh = blockIdx.x >> 5;
    const int b = bh >> 4, h = bh & 15;
#pragma unroll
    for (int u = 0; u < 2; ++u) {
        int f = t + u * 256;
        int n = f >> 3, c = f & 7;
        uint4 v = *(const uint4*)(qkvb + (size_t)(b * 2048 + nt * 64 + n) * 3072 + 2048 + h * 64 + c * 8);
        *(uint4*)&T[n][c * 8] = v;
    }
    __syncthreads();
    int d = t >> 2;
    u16 tmp[16];
#pragma unroll
    for (int i = 0; i < 16; ++i) tmp[i] = T[(t & 3) * 16 + i][d];
    u16* o = vt + ((size_t)bh * 64 + d) * 2048 + nt * 64 + (t & 3) * 16;
    *(uint4*)o       = *(uint4*)&tmp[0];
    *(uint4*)(o + 8) = *(uint4*)&tmp[8];
}

// ---------------- Flash attention: swapped QK^T, in-register softmax ----------------
// 4 waves x 32 q-rows = 128-row Q tile; KVBLK=64; 32x32x16 MFMA.
// S^T = mfma(A=K, B=Q): lane owns q=lane&31, 32 k-values in regs (2x f32x16).
// Partner half-exchange via __shfl_xor(.,32) (ds_bpermute — fully specified).
__global__ __launch_bounds__(256) void attn_mfma(
    const u16* __restrict__ qb, const u16* __restrict__ kbuf,
    const u16* __restrict__ vt, u16* __restrict__ attnb)
{
    __shared__ u16 Kl[2][4096];   // [64 k-rows][64 d] bf16, chunk-swizzled
    __shared__ u16 Vl[2][4096];   // [64 d-rows][64 n] bf16, chunk-swizzled

    const int t = threadIdx.x, l = t & 63, w = t >> 6;
    const int hi = l >> 5, lq = l & 31;
    const int qt = blockIdx.x & 15;       // N/128 = 16
    const int bh = blockIdx.x >> 4;
    const int b = bh >> 4, h = bh & 15;

    const int qrow = b * 2048 + qt * 128 + w * 32 + lq;
    bf16x8 qf[4];   // B-operand: Q[q=lane&31][16ds+8hi .. +8]
#pragma unroll
    for (int ds = 0; ds < 4; ++ds)
        qf[ds] = *(const bf16x8*)(qb + (size_t)qrow * 1024 + h * 64 + ds * 16 + hi * 8);

    f32x16 O0, O1;
#pragma unroll
    for (int r = 0; r < 16; ++r) { O0[r] = 0.f; O1[r] = 0.f; }
    float m = -1e30f, lsum = 0.f;

    auto stage = [&](int buf, int kt) {
#pragma unroll
        for (int u = 0; u < 2; ++u) {
            int p = w * 2 + u;                  // 0..7 -> 8 rows each
            int row = p * 8 + (l >> 3);
            int c = (l & 7) ^ (row & 7);        // pre-swizzled source chunk
            gload16(kbuf + (size_t)(b * 2048 + kt * 64 + row) * 1024 + h * 64 + c * 8,
                    &Kl[buf][p * 512]);
            gload16(vt + ((size_t)bh * 64 + row) * 2048 + kt * 64 + c * 8,
                    &Vl[buf][p * 512]);
        }
    };

    stage(0, 0);
    for (int kt = 0; kt < 32; ++kt) {
        __syncthreads();                        // drains stage(kt); frees buf[(kt+1)&1]
        if (kt + 1 < 32) stage((kt + 1) & 1, kt + 1);   // overlaps compute
        const u16* kl = &Kl[kt & 1][0];
        const u16* vl = &Vl[kt & 1][0];

        // S^T: S0 = k-rows 0..31, S1 = 32..63 (row k on regs, col q = lane&31)
        f32x16 S0, S1;
#pragma unroll
        for (int r = 0; r < 16; ++r) { S0[r] = 0.f; S1[r] = 0.f; }
#pragma unroll
        for (int ds = 0; ds < 4; ++ds) {
            int ch = ds * 2 + hi;
            int r0 = lq, r1 = lq + 32;
            bf16x8 kf0 = *(const bf16x8*)(kl + r0 * 64 + ((ch ^ (r0 & 7)) << 3));
            bf16x8 kf1 = *(const bf16x8*)(kl + r1 * 64 + ((ch ^ (r1 & 7)) << 3));
            S0 = MFMA32(kf0, qf[ds], S0);
            S1 = MFMA32(kf1, qf[ds], S1);
        }

        // in-lane max over 32 k-values + partner combine (shfl_xor 32)
        float mp[16];
#pragma unroll
        for (int r = 0; r < 16; ++r) mp[r] = fmaxf(S0[r], S1[r]);
#pragma unroll
        for (int s2 = 8; s2 > 0; s2 >>= 1)
#pragma unroll
            for (int r = 0; r < 8; ++r)
                if (r < s2) mp[r] = fmaxf(mp[r], mp[r + s2]);
        float mx = fmaxf(mp[0], __shfl_xor(mp[0], 32, 64));

        // defer-max (T13): only rescale when max grew by > 8 (log2 domain)
        if (!__all(mx - m <= 8.0f)) {
            float mn = fmaxf(m, mx);
            float al = exp2f(m - mn);
            lsum *= al;
#pragma unroll
            for (int r = 0; r < 16; ++r) { O0[r] *= al; O1[r] *= al; }
            m = mn;
        }

        // p = exp2(s - m) in place
#pragma unroll
        for (int r = 0; r < 16; ++r) {
            S0[r] = exp2f(S0[r] - m);
            S1[r] = exp2f(S1[r] - m);
        }

        // row sum (own 32 + partner 32)
        float sp[16];
#pragma unroll
        for (int r = 0; r < 16; ++r) sp[r] = S0[r] + S1[r];
#pragma unroll
        for (int s2 = 8; s2 > 0; s2 >>= 1)
#pragma unroll
            for (int r = 0; r < 8; ++r)
                if (r < s2) sp[r] += sp[r + s2];
        lsum += sp[0] + __shfl_xor(sp[0], 32, 64);

        // pack P -> PV B-operand fragments: cvt_pk + shfl_xor(32) half-exchange.
        // lane holds P^T[k(r,hi)][q=lq], k(r,hi) = (r&3)+8*(r>>2)+4*hi (+32 for S1).
        // pa[ks] elem e must be P[q][16ks+8hi+e].
        f32x16 PP[2] = { S0, S1 };
        bf16x8 pa[4];
#pragma unroll
        for (int kb2 = 0; kb2 < 2; ++kb2) {
            unsigned x[8], xp[8];
#pragma unroll
            for (int i = 0; i < 8; ++i)
                asm("v_cvt_pk_bf16_f32 %0, %1, %2"
                    : "=v"(x[i]) : "v"(PP[kb2][2 * i]), "v"(PP[kb2][2 * i + 1]));
#pragma unroll
            for (int i = 0; i < 8; ++i) xp[i] = __shfl_xor(x[i], 32, 64);
#pragma unroll
            for (int j = 0; j < 2; ++j) {
                // hi=0: {x[4j],x[4j+1],xp[4j],xp[4j+1]}  -> k = 16j+0..7
                // hi=1: {xp[4j+2],xp[4j+3],x[4j+2],x[4j+3]} -> k = 16j+8..15
                union { unsigned wv[4]; bf16x8 v; } uu;
                uu.wv[0] = hi ? xp[4 * j + 2] : x[4 * j + 0];
                uu.wv[1] = hi ? xp[4 * j + 3] : x[4 * j + 1];
                uu.wv[2] = hi ? x[4 * j + 2]  : xp[4 * j + 0];
                uu.wv[3] = hi ? x[4 * j + 3]  : xp[4 * j + 1];
                pa[kb2 * 2 + j] = uu.v;
            }
        }

        // O^T += V^T @ P^T  (A = V^T d-rows, B = pa)
#pragma unroll
        for (int ks = 0; ks < 4; ++ks) {
            int ch = ks * 2 + hi;
            int r0 = lq, r1 = lq + 32;
            bf16x8 vf0 = *(const bf16x8*)(vl + r0 * 64 + ((ch ^ (r0 & 7)) << 3));
            bf16x8 vf1 = *(const bf16x8*)(vl + r1 * 64 + ((ch ^ (r1 & 7)) << 3));
            O0 = MFMA32(vf0, pa[ks], O0);
            O1 = MFMA32(vf1, pa[ks], O1);
        }
    }

    // epilogue: O/l -> attnb; d = (r&3) + 8*(r>>2) + 4*hi + 32*db, q = lane&31
    float linv = 1.0f / lsum;
    f32x16 Ox[2] = { O0, O1 };
#pragma unroll
    for (int db = 0; db < 2; ++db) {
#pragma unroll
        for (int a = 0; a < 4; ++a) {
            int d0 = a * 8 + hi * 4 + db * 32;
            unsigned long long pk = 0;
#pragma unroll
            for (int bb = 0; bb < 4; ++bb)
                pk |= (unsigned long long)f2b(Ox[db][a * 4 + bb] * linv) << (16 * bb);
            *(unsigned long long*)(attnb + (size_t)qrow * 1024 + h * 64 + d0) = pk;
        }
    }
}

extern "C" void kernel_launch(void* const* d_in, const int* in_sizes, int n_in,
                              void* d_out, int out_size, void* d_ws, size_t ws_size,
                              hipStream_t stream)
{
    const float* x    = (const float*)d_in[0];
    const float* Wqkv = (const float*)d_in[1];
    const float* bqkv = (const float*)d_in[2];
    const float* gq   = (const float*)d_in[3];
    const float* gk   = (const float*)d_in[4];
    const float* Wout = (const float*)d_in[5];
    const float* bout = (const float*)d_in[6];
    float* out = (float*)d_out;

    char* ws = (char*)d_ws;
    u16* xb     = (u16*)(ws);                       // 8 MB
    u16* wqkvt  = (u16*)(ws + (8u << 20));          // 6 MB
    u16* woutt  = (u16*)(ws + (14u << 20));         // 2 MB
    u16* qkvb   = (u16*)(ws + (16u << 20));         // 24 MB
    u16* attnb  = (u16*)(ws + (16u << 20));         // 8 MB (overlays qkvb, used after)
    u16* qbuf   = (u16*)(ws + (40u << 20));         // 8 MB
    u16* kbuf   = (u16*)(ws + (48u << 20));         // 8 MB
    u16* vtb    = (u16*)(ws + (56u << 20));         // 8 MB

    cvt_f32_bf16<<<2048, 256, 0, stream>>>(x, xb, M_ * C_ / 8);
    cvt_wT<<<16 * 48, 256, 0, stream>>>(Wqkv, wqkvt, 1024, 3072);
    cvt_wT<<<16 * 16, 256, 0, stream>>>(Wout, woutt, 1024, 1024);

    gemm_bf16<<<dim3(24, 32), 256, 0, stream>>>(xb, wqkvt, bqkv, qkvb, M_, 3072, 1024, 1);
    rmsnorm_qk_b<<<32768, 256, 0, stream>>>(qkvb, gq, gk, qbuf, kbuf);
    v_transpose<<<1024, 256, 0, stream>>>(qkvb, vtb);
    attn_mfma<<<512, 256, 0, stream>>>(qbuf, kbuf, vtb, attnb);
    gemm_bf16<<<dim3(8, 32), 256, 0, stream>>>(attnb, woutt, bout, out, M_, 1024, 1024, 0);
}

// Round 5
// 166.979 us; speedup vs baseline: 6.0081x; 1.0426x over previous
//
#include <hip/hip_runtime.h>

#define B_ 2
#define N_ 2048
#define C_ 1024
#define H_ 16
#define D_ 64
#define M_ (B_*N_)   // 4096
#define LOG2E 1.44269504088896340736f

typedef __bf16 bf16x8 __attribute__((ext_vector_type(8)));
typedef float  f32x4  __attribute__((ext_vector_type(4)));
typedef float  f32x16 __attribute__((ext_vector_type(16)));
typedef unsigned short u16;

#define MFMA16(a, b, c) __builtin_amdgcn_mfma_f32_16x16x32_bf16(a, b, c, 0, 0, 0)
#define MFMA32(a, b, c) __builtin_amdgcn_mfma_f32_32x32x16_bf16(a, b, c, 0, 0, 0)

__device__ __forceinline__ u16 f2b(float f) {
    union { float f; unsigned int u; } v; v.f = f;
    unsigned int r = (v.u + 0x7fffu + ((v.u >> 16) & 1u)) >> 16;
    return (u16)r;
}
__device__ __forceinline__ float b2f(u16 h) {
    union { unsigned int u; float f; } v; v.u = ((unsigned int)h) << 16;
    return v.f;
}
__device__ __forceinline__ void gload16(const void* g, void* lds) {
    __builtin_amdgcn_global_load_lds(
        (const __attribute__((address_space(1))) unsigned int*)g,
        (__attribute__((address_space(3))) unsigned int*)lds, 16, 0, 0);
}

// ---------------- x f32 -> bf16 ----------------
__global__ __launch_bounds__(256) void cvt_f32_bf16(
    const float* __restrict__ src, u16* __restrict__ dst, int n8)
{
    int i = blockIdx.x * 256 + threadIdx.x;
    if (i >= n8) return;
    float4 a = *(const float4*)(src + (size_t)i * 8);
    float4 b = *(const float4*)(src + (size_t)i * 8 + 4);
    u16 tmp[8] = { f2b(a.x), f2b(a.y), f2b(a.z), f2b(a.w),
                   f2b(b.x), f2b(b.y), f2b(b.z), f2b(b.w) };
    *(uint4*)(dst + (size_t)i * 8) = *(uint4*)tmp;
}

// ---------------- W f32 [K][N] -> bf16 [N][K] (transpose) ----------------
__global__ __launch_bounds__(256) void cvt_wT(
    const float* __restrict__ W, u16* __restrict__ Wt, int K, int N)
{
    __shared__ u16 T[64][72];
    const int t = threadIdx.x;
    const int ntiles = N >> 6;
    const int kt = blockIdx.x / ntiles, ntl = blockIdx.x % ntiles;
#pragma unroll
    for (int u = 0; u < 2; ++u) {
        int f = t + u * 256;
        int r = f >> 3, c = f & 7;
        const float* p = W + (size_t)(kt * 64 + r) * N + ntl * 64 + c * 8;
        float4 a = *(const float4*)p;
        float4 b = *(const float4*)(p + 4);
        u16 tmp[8] = { f2b(a.x), f2b(a.y), f2b(a.z), f2b(a.w),
                       f2b(b.x), f2b(b.y), f2b(b.z), f2b(b.w) };
        *(uint4*)&T[r][c * 8] = *(uint4*)tmp;
    }
    __syncthreads();
    int n = t >> 2;
    u16 tmp[16];
#pragma unroll
    for (int i = 0; i < 16; ++i) tmp[i] = T[(t & 3) * 16 + i][n];
    u16* o = Wt + (size_t)(ntl * 64 + n) * K + kt * 64 + (t & 3) * 16;
    *(uint4*)o       = *(uint4*)&tmp[0];
    *(uint4*)(o + 8) = *(uint4*)&tmp[8];
}

// ---------------- GEMM bf16 MFMA: A[M][K] @ Bt[N][K]^T + bias ----------------
__global__ __launch_bounds__(256) void gemm_bf16(
    const u16* __restrict__ A, const u16* __restrict__ Bt,
    const float* __restrict__ bias, void* __restrict__ Cout,
    int M, int N, int K, int bf16out)
{
    __shared__ u16 Al[2][128 * 32];
    __shared__ u16 Bl[2][128 * 32];
    const int t = threadIdx.x, l = t & 63, w = t >> 6;
    const int wr = w >> 1, wc = w & 1;
    const int bm = blockIdx.y * 128, bn = blockIdx.x * 128;

    f32x4 acc[4][4];
#pragma unroll
    for (int i = 0; i < 4; ++i)
#pragma unroll
        for (int j = 0; j < 4; ++j) acc[i][j] = (f32x4){0.f, 0.f, 0.f, 0.f};

    const int srow = (l >> 2);
    const int schunk = (l & 3) ^ ((l >> 2) & 3);

    auto stage = [&](int buf, int k0) {
#pragma unroll
        for (int u = 0; u < 2; ++u) {
            int p = w * 2 + u;
            int r = p * 16 + srow;
            gload16(A + (size_t)(bm + r) * K + k0 + schunk * 8, &Al[buf][p * 512]);
            gload16(Bt + (size_t)(bn + r) * K + k0 + schunk * 8, &Bl[buf][p * 512]);
        }
    };

    stage(0, 0);
    const int NT = K / 32;
    const int g = l >> 4;
    for (int tt = 0; tt < NT; ++tt) {
        __syncthreads();
        if (tt + 1 < NT) stage((tt + 1) & 1, (tt + 1) * 32);
        const u16* al = &Al[tt & 1][0];
        const u16* bl = &Bl[tt & 1][0];
        bf16x8 af[4], bf[4];
#pragma unroll
        for (int mb = 0; mb < 4; ++mb) {
            int r = wr * 64 + mb * 16 + (l & 15);
            af[mb] = *(const bf16x8*)(al + r * 32 + ((g ^ (r & 3)) << 3));
            int n = wc * 64 + mb * 16 + (l & 15);
            bf[mb] = *(const bf16x8*)(bl + n * 32 + ((g ^ (n & 3)) << 3));
        }
        __builtin_amdgcn_s_setprio(1);
#pragma unroll
        for (int mb = 0; mb < 4; ++mb)
#pragma unroll
            for (int nb = 0; nb < 4; ++nb)
                acc[mb][nb] = MFMA16(af[mb], bf[nb], acc[mb][nb]);
        __builtin_amdgcn_s_setprio(0);
    }

#pragma unroll
    for (int mb = 0; mb < 4; ++mb) {
        int row = bm + wr * 64 + mb * 16 + (l >> 4) * 4;
#pragma unroll
        for (int nb = 0; nb < 4; ++nb) {
            int col = bn + wc * 64 + nb * 16 + (l & 15);
            float bv = bias[col];
#pragma unroll
            for (int r = 0; r < 4; ++r) {
                float v = acc[mb][nb][r] + bv;
                if (bf16out) ((u16*)Cout)[(size_t)(row + r) * N + col] = f2b(v);
                else        ((float*)Cout)[(size_t)(row + r) * N + col] = v;
            }
        }
    }
}

// ---------------- RMSNorm q,k; q folds softmax scale AND log2(e) ----------------
__global__ __launch_bounds__(256) void rmsnorm_qk_b(
    const u16* __restrict__ qkvb, const float* __restrict__ gq,
    const float* __restrict__ gk, u16* __restrict__ qb, u16* __restrict__ kb)
{
    const int t = threadIdx.x, lane = t & 63;
    const int vec = blockIdx.x * 4 + (t >> 6);
    const int row = vec >> 5;
    const int rem = vec & 31;
    const int s = rem >> 4, h = rem & 15;
    float v = b2f(qkvb[(size_t)row * 3072 + s * 1024 + h * 64 + lane]);
    float ss = v * v;
#pragma unroll
    for (int o = 32; o > 0; o >>= 1) ss += __shfl_xor(ss, o, 64);
    float inv = rsqrtf(fmaxf(ss, 1e-24f));
    const float* gm = s ? gk : gq;
    float scale = s ? 8.0f : LOG2E;
    u16* outp = s ? kb : qb;
    outp[(size_t)row * 1024 + h * 64 + lane] = f2b(v * inv * gm[h * 64 + lane] * scale);
}

// ---------------- V -> Vt global transpose: vt[bh][d][n] ----------------
__global__ __launch_bounds__(256) void v_transpose(
    const u16* __restrict__ qkvb, u16* __restrict__ vt)
{
    __shared__ u16 T[64][72];
    const int t = threadIdx.x;
    const int nt = blockIdx.x & 31;
    const int bh = blockIdx.x >> 5;
    const int b = bh >> 4, h = bh & 15;
#pragma unroll
    for (int u = 0; u < 2; ++u) {
        int f = t + u * 256;
        int n = f >> 3, c = f & 7;
        uint4 v = *(const uint4*)(qkvb + (size_t)(b * 2048 + nt * 64 + n) * 3072 + 2048 + h * 64 + c * 8);
        *(uint4*)&T[n][c * 8] = v;
    }
    __syncthreads();
    int d = t >> 2;
    u16 tmp[16];
#pragma unroll
    for (int i = 0; i < 16; ++i) tmp[i] = T[(t & 3) * 16 + i][d];
    u16* o = vt + ((size_t)bh * 64 + d) * 2048 + nt * 64 + (t & 3) * 16;
    *(uint4*)o       = *(uint4*)&tmp[0];
    *(uint4*)(o + 8) = *(uint4*)&tmp[8];
}

// ---------------- Flash attention, KV-split x2, pi-permuted K staging ----------------
// 4 waves x 32 q-rows; KVBLK=64, 16 tiles per split.
// K rows staged with pi(k) = k^12 when (k>>2)&3 in {1,2}: makes the PV B-operand
// pack = direct cvt_pk of S registers (no cross-lane exchange).
__global__ __launch_bounds__(256, 4) void attn_mfma(
    const u16* __restrict__ qb, const u16* __restrict__ kbuf,
    const u16* __restrict__ vt, u16* __restrict__ opart, float* __restrict__ mlw)
{
    __shared__ u16 Kl[2][4096];
    __shared__ u16 Vl[2][4096];

    const int t = threadIdx.x, l = t & 63, w = t >> 6;
    const int hi = l >> 5, lq = l & 31;
    // XCD-chunked swizzle: XCD x runs orig in [x*128, x*128+128) -> 4 heads/XCD
    const int orig = ((blockIdx.x & 7) << 7) | (blockIdx.x >> 3);
    const int qt = orig & 15;
    const int s  = (orig >> 4) & 1;
    const int bh = orig >> 5;
    const int b = bh >> 4, h = bh & 15;
    const int bq = bh * 16 + qt;

    const int qrow = b * 2048 + qt * 128 + w * 32 + lq;
    bf16x8 qf[4];
#pragma unroll
    for (int ds = 0; ds < 4; ++ds)
        qf[ds] = *(const bf16x8*)(qb + (size_t)qrow * 1024 + h * 64 + ds * 16 + hi * 8);

    f32x16 O0, O1;
#pragma unroll
    for (int r = 0; r < 16; ++r) { O0[r] = 0.f; O1[r] = 0.f; }
    float m = -1e30f, lsum = 0.f;

    auto stage = [&](int buf, int kt) {
#pragma unroll
        for (int u = 0; u < 2; ++u) {
            int p = w * 2 + u;
            int row = p * 8 + (l >> 3);          // LDS slot row
            int c = (l & 7) ^ (row & 7);         // pre-swizzled source chunk
            int r5 = row & 31;
            int bb = (r5 >> 2) & 3;
            int grow = (row & 32) | ((bb == 1 || bb == 2) ? (r5 ^ 12) : r5);
            gload16(kbuf + (size_t)(b * 2048 + s * 1024 + kt * 64 + grow) * 1024 + h * 64 + c * 8,
                    &Kl[buf][p * 512]);
            gload16(vt + ((size_t)bh * 64 + row) * 2048 + s * 1024 + kt * 64 + c * 8,
                    &Vl[buf][p * 512]);
        }
    };

    stage(0, 0);
    for (int kt = 0; kt < 16; ++kt) {
        __syncthreads();
        if (kt + 1 < 16) stage((kt + 1) & 1, kt + 1);
        const u16* kl = &Kl[kt & 1][0];
        const u16* vl = &Vl[kt & 1][0];

        // S^T = K·Q^T (rows = pi-permuted k, cols = q on lane&31)
        f32x16 S0, S1;
#pragma unroll
        for (int r = 0; r < 16; ++r) { S0[r] = 0.f; S1[r] = 0.f; }
        __builtin_amdgcn_s_setprio(1);
#pragma unroll
        for (int ds = 0; ds < 4; ++ds) {
            int ch = ds * 2 + hi;
            int r0 = lq, r1 = lq + 32;
            bf16x8 kf0 = *(const bf16x8*)(kl + r0 * 64 + ((ch ^ (r0 & 7)) << 3));
            bf16x8 kf1 = *(const bf16x8*)(kl + r1 * 64 + ((ch ^ (r1 & 7)) << 3));
            S0 = MFMA32(kf0, qf[ds], S0);
            S1 = MFMA32(kf1, qf[ds], S1);
        }
        __builtin_amdgcn_s_setprio(0);

        // in-lane max + single partner combine
        float mp[16];
#pragma unroll
        for (int r = 0; r < 16; ++r) mp[r] = fmaxf(S0[r], S1[r]);
#pragma unroll
        for (int s2 = 8; s2 > 0; s2 >>= 1)
#pragma unroll
            for (int r = 0; r < 8; ++r)
                if (r < s2) mp[r] = fmaxf(mp[r], mp[r + s2]);
        float mx = fmaxf(mp[0], __shfl_xor(mp[0], 32, 64));

        // defer-max (T13)
        if (!__all(mx - m <= 8.0f)) {
            float mn = fmaxf(m, mx);
            float al = exp2f(m - mn);
            lsum *= al;
#pragma unroll
            for (int r = 0; r < 16; ++r) { O0[r] *= al; O1[r] *= al; }
            m = mn;
        }

#pragma unroll
        for (int r = 0; r < 16; ++r) {
            S0[r] = exp2f(S0[r] - m);
            S1[r] = exp2f(S1[r] - m);
        }

        float sp[16];
#pragma unroll
        for (int r = 0; r < 16; ++r) sp[r] = S0[r] + S1[r];
#pragma unroll
        for (int s2 = 8; s2 > 0; s2 >>= 1)
#pragma unroll
            for (int r = 0; r < 8; ++r)
                if (r < s2) sp[r] += sp[r + s2];
        lsum += sp[0] + __shfl_xor(sp[0], 32, 64);

        // pack P: pi-permutation makes this a straight cvt_pk of registers
        bf16x8 pa[4];
        {
            unsigned x0[8], x1[8];
#pragma unroll
            for (int i = 0; i < 8; ++i) {
                asm("v_cvt_pk_bf16_f32 %0, %1, %2"
                    : "=v"(x0[i]) : "v"(S0[2 * i]), "v"(S0[2 * i + 1]));
                asm("v_cvt_pk_bf16_f32 %0, %1, %2"
                    : "=v"(x1[i]) : "v"(S1[2 * i]), "v"(S1[2 * i + 1]));
            }
            union { unsigned wv[4]; bf16x8 v; } uu;
            uu.wv[0] = x0[0]; uu.wv[1] = x0[1]; uu.wv[2] = x0[2]; uu.wv[3] = x0[3];
            pa[0] = uu.v;
            uu.wv[0] = x0[4]; uu.wv[1] = x0[5]; uu.wv[2] = x0[6]; uu.wv[3] = x0[7];
            pa[1] = uu.v;
            uu.wv[0] = x1[0]; uu.wv[1] = x1[1]; uu.wv[2] = x1[2]; uu.wv[3] = x1[3];
            pa[2] = uu.v;
            uu.wv[0] = x1[4]; uu.wv[1] = x1[5]; uu.wv[2] = x1[6]; uu.wv[3] = x1[7];
            pa[3] = uu.v;
        }

        // O^T += V^T @ P^T
        __builtin_amdgcn_s_setprio(1);
#pragma unroll
        for (int ks = 0; ks < 4; ++ks) {
            int ch = ks * 2 + hi;
            int r0 = lq, r1 = lq + 32;
            bf16x8 vf0 = *(const bf16x8*)(vl + r0 * 64 + ((ch ^ (r0 & 7)) << 3));
            bf16x8 vf1 = *(const bf16x8*)(vl + r1 * 64 + ((ch ^ (r1 & 7)) << 3));
            O0 = MFMA32(vf0, pa[ks], O0);
            O1 = MFMA32(vf1, pa[ks], O1);
        }
        __builtin_amdgcn_s_setprio(0);
    }

    // epilogue: partial O (unnormalized, bf16) + (m, lsum)
    const size_t obase = ((size_t)(s * 512 + bq) * 128 + (w * 32 + lq)) * 64;
    f32x16 Ox[2] = { O0, O1 };
#pragma unroll
    for (int db = 0; db < 2; ++db) {
#pragma unroll
        for (int a = 0; a < 4; ++a) {
            int d0 = a * 8 + hi * 4 + db * 32;
            unsigned long long pk = 0;
#pragma unroll
            for (int bb = 0; bb < 4; ++bb)
                pk |= (unsigned long long)f2b(Ox[db][a * 4 + bb]) << (16 * bb);
            *(unsigned long long*)(opart + obase + d0) = pk;
        }
    }
    if (hi == 0) {
        float2 v; v.x = m; v.y = lsum;
        *(float2*)(mlw + ((size_t)(s * 512 + bq) * 128 + (w * 32 + lq)) * 2) = v;
    }
}

// ---------------- combine the 2 KV-splits ----------------
__global__ __launch_bounds__(256) void attn_combine(
    const u16* __restrict__ opart, const float* __restrict__ mlw,
    u16* __restrict__ attnb)
{
    const int t = threadIdx.x;
    const int bq = blockIdx.x;            // bh*16 + qt
    const int bh = bq >> 4, qt = bq & 15;
    const int b = bh >> 4, h = bh & 15;
    const int q = t >> 1, dh = (t & 1) << 5;
    const u16* p0 = opart + ((size_t)bq * 128 + q) * 64 + dh;
    const u16* p1 = opart + ((size_t)(512 + bq) * 128 + q) * 64 + dh;
    float2 v0 = *(const float2*)(mlw + ((size_t)bq * 128 + q) * 2);
    float2 v1 = *(const float2*)(mlw + ((size_t)(512 + bq) * 128 + q) * 2);
    float mm = fmaxf(v0.x, v1.x);
    float a0 = exp2f(v0.x - mm), a1 = exp2f(v1.x - mm);
    float linv = 1.0f / (v0.y * a0 + v1.y * a1);
    a0 *= linv; a1 *= linv;
    u16 ov[32];
#pragma unroll
    for (int u = 0; u < 4; ++u) {
        uint4 x0 = *(const uint4*)(p0 + u * 8);
        uint4 x1 = *(const uint4*)(p1 + u * 8);
        const u16* e0 = (const u16*)&x0;
        const u16* e1 = (const u16*)&x1;
#pragma unroll
        for (int e = 0; e < 8; ++e)
            ov[u * 8 + e] = f2b(b2f(e0[e]) * a0 + b2f(e1[e]) * a1);
    }
    u16* o = attnb + (size_t)(b * 2048 + qt * 128 + q) * 1024 + h * 64 + dh;
#pragma unroll
    for (int u = 0; u < 4; ++u)
        *(uint4*)(o + u * 8) = *(uint4*)&ov[u * 8];
}

extern "C" void kernel_launch(void* const* d_in, const int* in_sizes, int n_in,
                              void* d_out, int out_size, void* d_ws, size_t ws_size,
                              hipStream_t stream)
{
    const float* x    = (const float*)d_in[0];
    const float* Wqkv = (const float*)d_in[1];
    const float* bqkv = (const float*)d_in[2];
    const float* gq   = (const float*)d_in[3];
    const float* gk   = (const float*)d_in[4];
    const float* Wout = (const float*)d_in[5];
    const float* bout = (const float*)d_in[6];
    float* out = (float*)d_out;

    char* ws = (char*)d_ws;
    u16* xb     = (u16*)(ws);                       // 8 MB   [cvt -> gemm1]
    u16* wqkvt  = (u16*)(ws + (8u << 20));          // 6 MB   [cvt -> gemm1]
    u16* woutt  = (u16*)(ws + (14u << 20));         // 2 MB   [cvt -> gemm2]
    u16* qkvb   = (u16*)(ws + (16u << 20));         // 24 MB  [gemm1 -> rms, vT]
    u16* qbuf   = (u16*)(ws + (40u << 20));         // 8 MB   [rms -> attn]
    u16* kbuf   = (u16*)(ws + (48u << 20));         // 8 MB   [rms -> attn]
    u16* vtb    = (u16*)(ws + (56u << 20));         // 8 MB   [vT -> attn]
    u16* attnb  = (u16*)(ws);                       // 8 MB   [combine -> gemm2] (xb dead)
    u16* opart  = (u16*)(ws + (16u << 20));         // 16 MB  [attn -> combine] (qkvb dead)
    float* mlw  = (float*)(ws + (32u << 20));       // 1 MB   [attn -> combine]

    cvt_f32_bf16<<<2048, 256, 0, stream>>>(x, xb, M_ * C_ / 8);
    cvt_wT<<<16 * 48, 256, 0, stream>>>(Wqkv, wqkvt, 1024, 3072);
    cvt_wT<<<16 * 16, 256, 0, stream>>>(Wout, woutt, 1024, 1024);

    gemm_bf16<<<dim3(24, 32), 256, 0, stream>>>(xb, wqkvt, bqkv, qkvb, M_, 3072, 1024, 1);
    rmsnorm_qk_b<<<32768, 256, 0, stream>>>(qkvb, gq, gk, qbuf, kbuf);
    v_transpose<<<1024, 256, 0, stream>>>(qkvb, vtb);
    attn_mfma<<<1024, 256, 0, stream>>>(qbuf, kbuf, vtb, opart, mlw);
    attn_combine<<<512, 256, 0, stream>>>(opart, mlw, attnb);
    gemm_bf16<<<dim3(8, 32), 256, 0, stream>>>(attnb, woutt, bout, out, M_, 1024, 1024, 0);
}

// Round 6
// 145.086 us; speedup vs baseline: 6.9147x; 1.1509x over previous
//
#include <hip/hip_runtime.h>

#define B_ 2
#define N_ 2048
#define C_ 1024
#define H_ 16
#define D_ 64
#define M_ (B_*N_)   // 4096
#define LOG2E 1.44269504088896340736f

typedef __bf16 bf16x8 __attribute__((ext_vector_type(8)));
typedef float  f32x4  __attribute__((ext_vector_type(4)));
typedef float  f32x16 __attribute__((ext_vector_type(16)));
typedef unsigned short u16;

#define MFMA16(a, b, c) __builtin_amdgcn_mfma_f32_16x16x32_bf16(a, b, c, 0, 0, 0)
#define MFMA32(a, b, c) __builtin_amdgcn_mfma_f32_32x32x16_bf16(a, b, c, 0, 0, 0)

__device__ __forceinline__ u16 f2b(float f) {
    union { float f; unsigned int u; } v; v.f = f;
    unsigned int r = (v.u + 0x7fffu + ((v.u >> 16) & 1u)) >> 16;
    return (u16)r;
}
__device__ __forceinline__ float b2f(u16 h) {
    union { unsigned int u; float f; } v; v.u = ((unsigned int)h) << 16;
    return v.f;
}
__device__ __forceinline__ void gload16(const void* g, void* lds) {
    __builtin_amdgcn_global_load_lds(
        (const __attribute__((address_space(1))) unsigned int*)g,
        (__attribute__((address_space(3))) unsigned int*)lds, 16, 0, 0);
}

// ---------------- fused prep: x->bf16 (2048 blk) | WqkvT (768) | WoutT (256) ----------------
__global__ __launch_bounds__(256) void prep(
    const float* __restrict__ x, const float* __restrict__ Wqkv,
    const float* __restrict__ Wout, u16* __restrict__ xb,
    u16* __restrict__ wqkvt, u16* __restrict__ woutt)
{
    __shared__ u16 T[64][72];
    const int t = threadIdx.x;
    const int bid = blockIdx.x;
    if (bid < 2048) {
        int i = bid * 256 + t;
        float4 a = *(const float4*)(x + (size_t)i * 8);
        float4 b = *(const float4*)(x + (size_t)i * 8 + 4);
        u16 tmp[8] = { f2b(a.x), f2b(a.y), f2b(a.z), f2b(a.w),
                       f2b(b.x), f2b(b.y), f2b(b.z), f2b(b.w) };
        *(uint4*)(xb + (size_t)i * 8) = *(uint4*)tmp;
        return;
    }
    const float* W; u16* Wt; int K, N, blk;
    if (bid < 2048 + 768) { W = Wqkv; Wt = wqkvt; K = 1024; N = 3072; blk = bid - 2048; }
    else                  { W = Wout; Wt = woutt; K = 1024; N = 1024; blk = bid - 2816; }
    const int ntiles = N >> 6;
    const int kt = blk / ntiles, ntl = blk % ntiles;
#pragma unroll
    for (int u = 0; u < 2; ++u) {
        int f = t + u * 256;
        int r = f >> 3, c = f & 7;
        const float* p = W + (size_t)(kt * 64 + r) * N + ntl * 64 + c * 8;
        float4 a = *(const float4*)p;
        float4 b = *(const float4*)(p + 4);
        u16 tmp[8] = { f2b(a.x), f2b(a.y), f2b(a.z), f2b(a.w),
                       f2b(b.x), f2b(b.y), f2b(b.z), f2b(b.w) };
        *(uint4*)&T[r][c * 8] = *(uint4*)tmp;
    }
    __syncthreads();
    int n = t >> 2;
    u16 tmp[16];
#pragma unroll
    for (int i = 0; i < 16; ++i) tmp[i] = T[(t & 3) * 16 + i][n];
    u16* o = Wt + (size_t)(ntl * 64 + n) * K + kt * 64 + (t & 3) * 16;
    *(uint4*)o       = *(uint4*)&tmp[0];
    *(uint4*)(o + 8) = *(uint4*)&tmp[8];
}

// ---------------- GEMM bf16 MFMA: A[M][K] @ Bt[N][K]^T + bias ----------------
__global__ __launch_bounds__(256) void gemm_bf16(
    const u16* __restrict__ A, const u16* __restrict__ Bt,
    const float* __restrict__ bias, void* __restrict__ Cout,
    int M, int N, int K, int bf16out)
{
    __shared__ u16 Al[2][128 * 32];
    __shared__ u16 Bl[2][128 * 32];
    const int t = threadIdx.x, l = t & 63, w = t >> 6;
    const int wr = w >> 1, wc = w & 1;
    const int bm = blockIdx.y * 128, bn = blockIdx.x * 128;

    f32x4 acc[4][4];
#pragma unroll
    for (int i = 0; i < 4; ++i)
#pragma unroll
        for (int j = 0; j < 4; ++j) acc[i][j] = (f32x4){0.f, 0.f, 0.f, 0.f};

    const int srow = (l >> 2);
    const int schunk = (l & 3) ^ ((l >> 2) & 3);

    auto stage = [&](int buf, int k0) {
#pragma unroll
        for (int u = 0; u < 2; ++u) {
            int p = w * 2 + u;
            int r = p * 16 + srow;
            gload16(A + (size_t)(bm + r) * K + k0 + schunk * 8, &Al[buf][p * 512]);
            gload16(Bt + (size_t)(bn + r) * K + k0 + schunk * 8, &Bl[buf][p * 512]);
        }
    };

    stage(0, 0);
    const int NT = K / 32;
    const int g = l >> 4;
    for (int tt = 0; tt < NT; ++tt) {
        __syncthreads();
        if (tt + 1 < NT) stage((tt + 1) & 1, (tt + 1) * 32);
        const u16* al = &Al[tt & 1][0];
        const u16* bl = &Bl[tt & 1][0];
        bf16x8 af[4], bf[4];
#pragma unroll
        for (int mb = 0; mb < 4; ++mb) {
            int r = wr * 64 + mb * 16 + (l & 15);
            af[mb] = *(const bf16x8*)(al + r * 32 + ((g ^ (r & 3)) << 3));
            int n = wc * 64 + mb * 16 + (l & 15);
            bf[mb] = *(const bf16x8*)(bl + n * 32 + ((g ^ (n & 3)) << 3));
        }
        __builtin_amdgcn_s_setprio(1);
#pragma unroll
        for (int mb = 0; mb < 4; ++mb)
#pragma unroll
            for (int nb = 0; nb < 4; ++nb)
                acc[mb][nb] = MFMA16(af[mb], bf[nb], acc[mb][nb]);
        __builtin_amdgcn_s_setprio(0);
    }

#pragma unroll
    for (int mb = 0; mb < 4; ++mb) {
        int row = bm + wr * 64 + mb * 16 + (l >> 4) * 4;
#pragma unroll
        for (int nb = 0; nb < 4; ++nb) {
            int col = bn + wc * 64 + nb * 16 + (l & 15);
            float bv = bias[col];
#pragma unroll
            for (int r = 0; r < 4; ++r) {
                float v = acc[mb][nb][r] + bv;
                if (bf16out) ((u16*)Cout)[(size_t)(row + r) * N + col] = f2b(v);
                else        ((float*)Cout)[(size_t)(row + r) * N + col] = v;
            }
        }
    }
}

// ---------------- fused: vectorized RMSNorm q,k (1024 blk) | V transpose (1024 blk) ----------------
__global__ __launch_bounds__(256) void rms_vt(
    const u16* __restrict__ qkvb, const float* __restrict__ gq,
    const float* __restrict__ gk, u16* __restrict__ qb, u16* __restrict__ kb,
    u16* __restrict__ vt)
{
    __shared__ u16 T[64][72];
    const int t = threadIdx.x;
    if (blockIdx.x < 1024) {
        // RMSNorm: 4 rows/block, 1 wave/row; lane group of 8 owns one 64-vec
        const int row = blockIdx.x * 4 + (t >> 6), lane = t & 63;
        const u16* base = qkvb + (size_t)row * 3072;
        const int d0 = (lane & 7) * 8;
#pragma unroll
        for (int i = 0; i < 4; ++i) {
            int off = i * 512 + lane * 8;
            uint4 xv = *(const uint4*)(base + off);
            const u16* e = (const u16*)&xv;
            float f[8]; float ss = 0.f;
#pragma unroll
            for (int j = 0; j < 8; ++j) { f[j] = b2f(e[j]); ss += f[j] * f[j]; }
            ss += __shfl_xor(ss, 1, 64);
            ss += __shfl_xor(ss, 2, 64);
            ss += __shfl_xor(ss, 4, 64);
            float inv = rsqrtf(fmaxf(ss, 1e-24f));
            int vec = i * 8 + (lane >> 3);
            int isK = vec >> 4, h = vec & 15;
            const float* gm = (isK ? gk : gq) + h * 64 + d0;
            float4 g0 = *(const float4*)gm;
            float4 g1 = *(const float4*)(gm + 4);
            float gg[8] = { g0.x, g0.y, g0.z, g0.w, g1.x, g1.y, g1.z, g1.w };
            float scale = isK ? 8.0f : LOG2E;
            u16 ov[8];
#pragma unroll
            for (int j = 0; j < 8; ++j) ov[j] = f2b(f[j] * inv * gg[j] * scale);
            u16* dst = (isK ? kb : qb) + (size_t)row * 1024 + h * 64 + d0;
            *(uint4*)dst = *(uint4*)ov;
        }
        return;
    }
    // V transpose: vt[bh][d][n]
    const int blk = blockIdx.x - 1024;
    const int nt = blk & 31;
    const int bh = blk >> 5;
    const int b = bh >> 4, h = bh & 15;
#pragma unroll
    for (int u = 0; u < 2; ++u) {
        int f = t + u * 256;
        int n = f >> 3, c = f & 7;
        uint4 v = *(const uint4*)(qkvb + (size_t)(b * 2048 + nt * 64 + n) * 3072 + 2048 + h * 64 + c * 8);
        *(uint4*)&T[n][c * 8] = v;
    }
    __syncthreads();
    int d = t >> 2;
    u16 tmp[16];
#pragma unroll
    for (int i = 0; i < 16; ++i) tmp[i] = T[(t & 3) * 16 + i][d];
    u16* o = vt + ((size_t)bh * 64 + d) * 2048 + nt * 64 + (t & 3) * 16;
    *(uint4*)o       = *(uint4*)&tmp[0];
    *(uint4*)(o + 8) = *(uint4*)&tmp[8];
}

// ---------------- Flash attention, KV-split x4, fixed softmax max ----------------
// Scores (log2 domain) bounded: |q.k/sqrtD * log2e| <= 8*log2e < 12 (Cauchy-Schwarz,
// RMS-normed q,k) -> fixed m=12, no max pass, no rescale, partials share m.
__global__ __launch_bounds__(256, 4) void attn_mfma(
    const u16* __restrict__ qb, const u16* __restrict__ kbuf,
    const u16* __restrict__ vt, u16* __restrict__ op012, u16* __restrict__ op3,
    float* __restrict__ lsums)
{
    __shared__ u16 Kl[2][4096];
    __shared__ u16 Vl[2][4096];

    const int t = threadIdx.x, l = t & 63, w = t >> 6;
    const int hi = l >> 5, lq = l & 31;
    const int orig = ((blockIdx.x & 7) << 8) | (blockIdx.x >> 3);   // XCD-chunked
    const int qt = orig & 15;
    const int s  = (orig >> 4) & 3;        // KV split 0..3 (512 rows each)
    const int bh = orig >> 6;
    const int b = bh >> 4, h = bh & 15;
    const int bq = bh * 16 + qt;
    const int kv0 = s * 512;

    const int qrow = b * 2048 + qt * 128 + w * 32 + lq;
    bf16x8 qf[4];
#pragma unroll
    for (int ds = 0; ds < 4; ++ds)
        qf[ds] = *(const bf16x8*)(qb + (size_t)qrow * 1024 + h * 64 + ds * 16 + hi * 8);

    f32x16 O0, O1;
#pragma unroll
    for (int r = 0; r < 16; ++r) { O0[r] = 0.f; O1[r] = 0.f; }
    float lsum = 0.f;

    auto stage = [&](int buf, int kt) {
#pragma unroll
        for (int u = 0; u < 2; ++u) {
            int p = w * 2 + u;
            int row = p * 8 + (l >> 3);          // LDS slot row
            int c = (l & 7) ^ (row & 7);         // pre-swizzled source chunk
            int r5 = row & 31;
            int bb = (r5 >> 2) & 3;
            int grow = (row & 32) | ((bb == 1 || bb == 2) ? (r5 ^ 12) : r5);
            gload16(kbuf + (size_t)(b * 2048 + kv0 + kt * 64 + grow) * 1024 + h * 64 + c * 8,
                    &Kl[buf][p * 512]);
            gload16(vt + ((size_t)bh * 64 + row) * 2048 + kv0 + kt * 64 + c * 8,
                    &Vl[buf][p * 512]);
        }
    };

    stage(0, 0);
    for (int kt = 0; kt < 8; ++kt) {
        __syncthreads();
        if (kt + 1 < 8) stage((kt + 1) & 1, kt + 1);
        const u16* kl = &Kl[kt & 1][0];
        const u16* vl = &Vl[kt & 1][0];

        // S^T = K.Q^T (rows = pi-permuted k, cols = q on lane&31)
        f32x16 S0, S1;
#pragma unroll
        for (int r = 0; r < 16; ++r) { S0[r] = 0.f; S1[r] = 0.f; }
        __builtin_amdgcn_s_setprio(1);
#pragma unroll
        for (int ds = 0; ds < 4; ++ds) {
            int ch = ds * 2 + hi;
            int r0 = lq, r1 = lq + 32;
            bf16x8 kf0 = *(const bf16x8*)(kl + r0 * 64 + ((ch ^ (r0 & 7)) << 3));
            bf16x8 kf1 = *(const bf16x8*)(kl + r1 * 64 + ((ch ^ (r1 & 7)) << 3));
            S0 = MFMA32(kf0, qf[ds], S0);
            S1 = MFMA32(kf1, qf[ds], S1);
        }
        __builtin_amdgcn_s_setprio(0);

        // P = exp2(S - 12), fixed max; accumulate row-sum (own half only)
#pragma unroll
        for (int r = 0; r < 16; ++r) {
            S0[r] = exp2f(S0[r] - 12.0f);
            S1[r] = exp2f(S1[r] - 12.0f);
        }
        float sp[16];
#pragma unroll
        for (int r = 0; r < 16; ++r) sp[r] = S0[r] + S1[r];
#pragma unroll
        for (int s2 = 8; s2 > 0; s2 >>= 1)
#pragma unroll
            for (int r = 0; r < 8; ++r)
                if (r < s2) sp[r] += sp[r + s2];
        lsum += sp[0];

        // pack P: pi-permutation -> straight cvt_pk of registers
        bf16x8 pa[4];
        {
            unsigned x0[8], x1[8];
#pragma unroll
            for (int i = 0; i < 8; ++i) {
                asm("v_cvt_pk_bf16_f32 %0, %1, %2"
                    : "=v"(x0[i]) : "v"(S0[2 * i]), "v"(S0[2 * i + 1]));
                asm("v_cvt_pk_bf16_f32 %0, %1, %2"
                    : "=v"(x1[i]) : "v"(S1[2 * i]), "v"(S1[2 * i + 1]));
            }
            union { unsigned wv[4]; bf16x8 v; } uu;
            uu.wv[0] = x0[0]; uu.wv[1] = x0[1]; uu.wv[2] = x0[2]; uu.wv[3] = x0[3];
            pa[0] = uu.v;
            uu.wv[0] = x0[4]; uu.wv[1] = x0[5]; uu.wv[2] = x0[6]; uu.wv[3] = x0[7];
            pa[1] = uu.v;
            uu.wv[0] = x1[0]; uu.wv[1] = x1[1]; uu.wv[2] = x1[2]; uu.wv[3] = x1[3];
            pa[2] = uu.v;
            uu.wv[0] = x1[4]; uu.wv[1] = x1[5]; uu.wv[2] = x1[6]; uu.wv[3] = x1[7];
            pa[3] = uu.v;
        }

        // O^T += V^T @ P^T
        __builtin_amdgcn_s_setprio(1);
#pragma unroll
        for (int ks = 0; ks < 4; ++ks) {
            int ch = ks * 2 + hi;
            int r0 = lq, r1 = lq + 32;
            bf16x8 vf0 = *(const bf16x8*)(vl + r0 * 64 + ((ch ^ (r0 & 7)) << 3));
            bf16x8 vf1 = *(const bf16x8*)(vl + r1 * 64 + ((ch ^ (r1 & 7)) << 3));
            O0 = MFMA32(vf0, pa[ks], O0);
            O1 = MFMA32(vf1, pa[ks], O1);
        }
        __builtin_amdgcn_s_setprio(0);
    }

    // epilogue: unnormalized partial O (bf16) + lsum (f32, one lane per q-row)
    u16* ob = ((s == 3) ? op3 : op012 + (size_t)s * 4194304)
              + ((size_t)bq * 128 + (w * 32 + lq)) * 64;
    f32x16 Ox[2] = { O0, O1 };
#pragma unroll
    for (int db = 0; db < 2; ++db) {
#pragma unroll
        for (int a = 0; a < 4; ++a) {
            int d0 = a * 8 + hi * 4 + db * 32;
            unsigned long long pk = 0;
#pragma unroll
            for (int bb = 0; bb < 4; ++bb)
                pk |= (unsigned long long)f2b(Ox[db][a * 4 + bb]) << (16 * bb);
            *(unsigned long long*)(ob + d0) = pk;
        }
    }
    float ltot = lsum + __shfl_xor(lsum, 32, 64);
    if (hi == 0)
        lsums[((size_t)s * 512 + bq) * 128 + w * 32 + lq] = ltot;
}

// ---------------- combine the 4 KV-splits (shared m -> plain weighted sum) ----------------
__global__ __launch_bounds__(256) void attn_combine(
    const u16* __restrict__ op012, const u16* __restrict__ op3,
    const float* __restrict__ lsums, u16* __restrict__ attnb)
{
    const int t = threadIdx.x;
    const int bq = blockIdx.x >> 1, qh = blockIdx.x & 1;
    const int bh = bq >> 4, qt = bq & 15;
    const int b = bh >> 4, h = bh & 15;
    const int q = qh * 64 + (t >> 2), dseg = (t & 3) * 16;

    float l = 0.f;
#pragma unroll
    for (int sp = 0; sp < 4; ++sp)
        l += lsums[((size_t)sp * 512 + bq) * 128 + q];
    float linv = 1.0f / l;

    float acc[16];
#pragma unroll
    for (int e = 0; e < 16; ++e) acc[e] = 0.f;
#pragma unroll
    for (int sp = 0; sp < 4; ++sp) {
        const u16* p = ((sp == 3) ? op3 : op012 + (size_t)sp * 4194304)
                       + ((size_t)bq * 128 + q) * 64 + dseg;
        uint4 x0 = *(const uint4*)p;
        uint4 x1 = *(const uint4*)(p + 8);
        const u16* e0 = (const u16*)&x0;
        const u16* e1 = (const u16*)&x1;
#pragma unroll
        for (int e = 0; e < 8; ++e) { acc[e] += b2f(e0[e]); acc[8 + e] += b2f(e1[e]); }
    }
    u16 ov[16];
#pragma unroll
    for (int e = 0; e < 16; ++e) ov[e] = f2b(acc[e] * linv);
    u16* o = attnb + (size_t)(b * 2048 + qt * 128 + q) * 1024 + h * 64 + dseg;
    *(uint4*)o       = *(uint4*)&ov[0];
    *(uint4*)(o + 8) = *(uint4*)&ov[8];
}

extern "C" void kernel_launch(void* const* d_in, const int* in_sizes, int n_in,
                              void* d_out, int out_size, void* d_ws, size_t ws_size,
                              hipStream_t stream)
{
    const float* x    = (const float*)d_in[0];
    const float* Wqkv = (const float*)d_in[1];
    const float* bqkv = (const float*)d_in[2];
    const float* gq   = (const float*)d_in[3];
    const float* gk   = (const float*)d_in[4];
    const float* Wout = (const float*)d_in[5];
    const float* bout = (const float*)d_in[6];
    float* out = (float*)d_out;

    char* ws = (char*)d_ws;
    // region           live span                       alias
    u16* xb     = (u16*)(ws);               // prep -> gemm1
    u16* op3    = (u16*)(ws);               // attn -> combine   (xb dead)
    u16* wqkvt  = (u16*)(ws + ( 8u << 20)); // prep -> gemm1
    float* lsums= (float*)(ws + ( 8u << 20)); // attn -> combine (wqkvt dead)
    u16* woutt  = (u16*)(ws + (14u << 20)); // prep -> gemm2
    u16* qkvb   = (u16*)(ws + (16u << 20)); // gemm1 -> rms_vt
    u16* op012  = (u16*)(ws + (16u << 20)); // attn -> combine   (qkvb dead)
    u16* qbuf   = (u16*)(ws + (40u << 20)); // rms_vt -> attn
    u16* attnb  = (u16*)(ws + (40u << 20)); // combine -> gemm2  (qbuf dead)
    u16* kbuf   = (u16*)(ws + (48u << 20)); // rms_vt -> attn
    u16* vtb    = (u16*)(ws + (56u << 20)); // rms_vt -> attn

    prep<<<3072, 256, 0, stream>>>(x, Wqkv, Wout, xb, wqkvt, woutt);
    gemm_bf16<<<dim3(24, 32), 256, 0, stream>>>(xb, wqkvt, bqkv, qkvb, M_, 3072, 1024, 1);
    rms_vt<<<2048, 256, 0, stream>>>(qkvb, gq, gk, qbuf, kbuf, vtb);
    attn_mfma<<<2048, 256, 0, stream>>>(qbuf, kbuf, vtb, op012, op3, lsums);
    attn_combine<<<1024, 256, 0, stream>>>(op012, op3, lsums, attnb);
    gemm_bf16<<<dim3(8, 32), 256, 0, stream>>>(attnb, woutt, bout, out, M_, 1024, 1024, 0);
}